// Round 1
// baseline (671.940 us; speedup 1.0000x reference)
//
#include <hip/hip_runtime.h>

#define NB 32
#define NN 256
#define NI 16
#define NO 16
#define NC 64
#define NH 64
#define NE 4096

__device__ __forceinline__ float sigmoidf_(float x){ return 1.0f/(1.0f+__expf(-x)); }

// ---- runtime dtype detection ------------------------------------------------
// flags[0] != 0  -> masks are 1-byte bools; == 0 -> int32
// flags[1] != 0  -> edge_index is int32;    == 0 -> int64
__global__ void k_detect(const unsigned char* __restrict__ m8, const int* __restrict__ ei, int* flags){
  int t = blockIdx.x*256 + threadIdx.x;              // 32768 threads
  unsigned a = (unsigned)m8[t*4+1] | (unsigned)m8[t*4+2] | (unsigned)m8[t*4+3];
  if (__any(a != 0) && (threadIdx.x & 63) == 0) atomicOr(&flags[0], 1);
  unsigned b = 0;
  if (t < 4096) b = (unsigned)ei[2*t+1];
  if (__any(b != 0) && (threadIdx.x & 63) == 0) atomicOr(&flags[1], 1);
}

// ---- mask -------------------------------------------------------------------
__global__ void k_mask(const float* __restrict__ data, const unsigned char* __restrict__ m8,
                       const int* __restrict__ flags, float* __restrict__ dm){
  int i = blockIdx.x*256 + threadIdx.x;              // 131072
  int mv = flags[0] ? (int)m8[i] : ((const int*)m8)[i];
  dm[i] = mv ? data[i] : 0.0f;
}

// ---- GCN: degree / norms / dense adjacency ----------------------------------
__device__ __forceinline__ int edge_src(const int* ei, const int* flags, int e){
  return flags[1] ? ei[e] : ei[2*e];
}
__device__ __forceinline__ int edge_dst(const int* ei, const int* flags, int e){
  return flags[1] ? ei[NE + e] : ei[2*(NE + e)];
}

__global__ void k_deg(const int* __restrict__ ei, const int* __restrict__ flags, float* deg){
  int e = blockIdx.x*256 + threadIdx.x;
  if (e < NE) atomicAdd(&deg[edge_dst(ei, flags, e)], 1.0f);
}

__global__ void k_dinv(const float* __restrict__ deg, float* __restrict__ dinv, float* __restrict__ wadj){
  int n = threadIdx.x;                               // 256 threads, 1 block
  float di = rsqrtf(deg[n] + 2.0f);
  dinv[n] = di;
  wadj[n*NN + n] = 2.0f*di*di;                       // improved self-loop weight
}

__global__ void k_adj(const int* __restrict__ ei, const int* __restrict__ flags,
                      const float* __restrict__ dinv, float* wadj){
  int e = blockIdx.x*256 + threadIdx.x;
  if (e < NE){
    int s = edge_src(ei, flags, e), d = edge_dst(ei, flags, e);
    atomicAdd(&wadj[d*NN + s], dinv[s]*dinv[d]);
  }
}

// ---- xw = x @ gcn_w ----------------------------------------------------------
__global__ void k_xw(const float* __restrict__ dm, const float* __restrict__ gw, float* __restrict__ xw){
  int idx = blockIdx.x*256 + threadIdx.x;            // 524288
  int c = idx & 63, n = (idx>>6) & 255, b = idx>>14;
  const float* dmb = dm + b*NI*NN;
  float a = 0.f;
  #pragma unroll
  for (int i=0;i<NI;i++) a += dmb[i*NN + n]*gw[i*NC + c];
  xw[idx] = a;
}

// ---- h = relu(W_adj @ xw + b) -------------------------------------------------
__global__ void k_agg(const float* __restrict__ wadj, const float* __restrict__ xw,
                      const float* __restrict__ gb, float* __restrict__ h){
  int idx = blockIdx.x*256 + threadIdx.x;            // 524288
  int c = idx & 63, n = (idx>>6) & 255, b = idx>>14;
  const float* wr = wadj + n*NN;
  const float* xb = xw + b*NN*NC + c;
  float a = gb[c];
  #pragma unroll 4
  for (int m=0;m<NN;m++) a += wr[m]*xb[m*NC];
  h[idx] = fmaxf(a, 0.0f);
}

// ---- q,k projections (shared by spatial & temporal attention) ------------------
__global__ void k_qk(const float* __restrict__ src, const float* __restrict__ qw,
                     const float* __restrict__ qbias, const float* __restrict__ kw,
                     const float* __restrict__ kbias, float* __restrict__ q, float* __restrict__ kout){
  int idx = blockIdx.x*256 + threadIdx.x;            // 524288
  int c = idx & 63;
  const float* hr = src + (idx>>6)*NC;
  float aq = qbias[c], ak = kbias[c];
  #pragma unroll 8
  for (int cc=0; cc<NC; cc++){ float hv = hr[cc]; aq += hv*qw[cc*NC + c]; ak += hv*kw[cc*NC + c]; }
  q[idx] = aq; kout[idx] = ak;
}

// ---- fused attention: 8 query rows per block, transposed output write ---------
// out[((b*64+c)*256)+n] = (softmax(q k^T * scale) @ v)[b][n][c]
__global__ __launch_bounds__(256) void k_attn8(const float* __restrict__ q, const float* __restrict__ kmat,
                        const float* __restrict__ v, float* __restrict__ outp, float scale){
  int bidx = blockIdx.x; int b = bidx >> 5, n0 = (bidx & 31)*8;
  int t = threadIdx.x;
  __shared__ __align__(16) float qs[8][64];
  __shared__ float S[8][256];
  #pragma unroll
  for (int rep=0; rep<2; rep++){
    int j = rep*256 + t; int r = j>>6, c = j&63;
    qs[r][c] = q[((b<<8) + n0 + r)*NC + c];
  }
  __syncthreads();
  // scores: thread t = key column m
  float4 kr[16];
  const float4* kp = (const float4*)(kmat + ((b<<8) + t)*NC);
  #pragma unroll
  for (int i=0;i<16;i++) kr[i] = kp[i];
  #pragma unroll
  for (int r=0;r<8;r++){
    const float4* q4 = (const float4*)qs[r];
    float s = 0.f;
    #pragma unroll
    for (int i=0;i<16;i++){ float4 a=q4[i], bb=kr[i]; s += a.x*bb.x + a.y*bb.y + a.z*bb.z + a.w*bb.w; }
    S[r][t] = s*scale;
  }
  __syncthreads();
  // softmax: 32-lane group g owns row g
  {
    int g = t>>5, l = t&31;
    float vals[8];
    #pragma unroll
    for (int k2=0;k2<8;k2++) vals[k2] = S[g][l + (k2<<5)];
    float mx = vals[0];
    #pragma unroll
    for (int k2=1;k2<8;k2++) mx = fmaxf(mx, vals[k2]);
    #pragma unroll
    for (int off=16; off; off>>=1) mx = fmaxf(mx, __shfl_xor(mx, off));
    float sm = 0.f;
    #pragma unroll
    for (int k2=0;k2<8;k2++){ vals[k2] = __expf(vals[k2]-mx); sm += vals[k2]; }
    #pragma unroll
    for (int off=16; off; off>>=1) sm += __shfl_xor(sm, off);
    float rS = 1.0f/sm;
    #pragma unroll
    for (int k2=0;k2<8;k2++) S[g][l + (k2<<5)] = vals[k2]*rS;
  }
  __syncthreads();
  // PV: thread (rp, c) accumulates rows rp and rp+4
  int c = t & 63, rp = t >> 6;
  const float* vp = v + (b<<8)*NC + c;
  float a0 = 0.f, a1 = 0.f;
  #pragma unroll 4
  for (int m=0;m<NN;m++){
    float vv = vp[m*NC];
    a0 += S[rp][m]*vv;
    a1 += S[rp+4][m]*vv;
  }
  outp[(((b<<6)+c)<<8) + n0 + rp]     = a0;
  outp[(((b<<6)+c)<<8) + n0 + rp + 4] = a1;
}

// ---- GRU input gates (parallel over all timesteps) -----------------------------
__global__ void k_gi(const float* __restrict__ dm, const float* __restrict__ wih,
                     const float* __restrict__ bih, float* __restrict__ gi){
  int row = blockIdx.x;                              // b*256+t, grid 8192
  int j = threadIdx.x;                               // 0..191
  const float* xr = dm + row*NI;                     // rnn_in is a flat reshape of dm
  float a = bih[j];
  #pragma unroll
  for (int i=0;i<NI;i++) a += xr[i]*wih[j*NI + i];
  gi[row*192 + j] = a;
}

// ---- GRU sequential scan: one block per batch sample ---------------------------
__global__ __launch_bounds__(192) void k_gru(const float* __restrict__ gi, const float* __restrict__ whh,
                      const float* __restrict__ bhh, float* __restrict__ rnn){
  int b = blockIdx.x, j = threadIdx.x;
  __shared__ __align__(16) float hs[64];
  __shared__ float gh[192];
  float w[64];
  const float4* wr = (const float4*)(whh + j*NH);
  #pragma unroll
  for (int k4=0;k4<16;k4++){ float4 t4 = wr[k4]; w[k4*4]=t4.x; w[k4*4+1]=t4.y; w[k4*4+2]=t4.z; w[k4*4+3]=t4.w; }
  float bj = bhh[j];
  if (j < 64) hs[j] = 0.f;
  __syncthreads();
  const float* gib = gi + b*NN*192;
  for (int t=0;t<NN;t++){
    float a0=0.f,a1=0.f,a2=0.f,a3=0.f;
    #pragma unroll
    for (int k4=0;k4<16;k4++){
      float4 hv = *(const float4*)&hs[k4*4];
      a0 += w[k4*4+0]*hv.x; a1 += w[k4*4+1]*hv.y; a2 += w[k4*4+2]*hv.z; a3 += w[k4*4+3]*hv.w;
    }
    gh[j] = a0+a1+a2+a3+bj;
    __syncthreads();
    if (j < 64){
      const float* gr = gib + t*192;
      float r  = sigmoidf_(gr[j]      + gh[j]);
      float z  = sigmoidf_(gr[j+64]   + gh[j+64]);
      float nn = tanhf    (gr[j+128]  + r*gh[j+128]);
      float hn = (1.0f - z)*nn + z*hs[j];
      rnn[(b*NN + t)*NH + j] = hn;
      hs[j] = hn;
    }
    __syncthreads();
  }
}

// ---- embed = concat([rnn_out, se]) flattened -----------------------------------
__global__ void k_embed(const float* __restrict__ rnn, const float* __restrict__ h, float* __restrict__ em){
  int idx = blockIdx.x*256 + threadIdx.x;            // 1048576
  int b = idx >> 15, r = idx & 32767;
  int n = r >> 7, c = r & 127;
  float v;
  if (c < 64) v = rnn[((b<<8) + n)*NH + c];
  else { int f = (n<<6) + (c-64); v = h[(b<<14) + ((f&255)<<6) + (f>>8)]; }
  em[idx] = v;
}

// ---- init out rows with bias ----------------------------------------------------
__global__ void k_binit(const float* __restrict__ bias, float* __restrict__ o){
  int idx = blockIdx.x*256 + threadIdx.x;            // 131072
  o[idx] = bias[idx & 4095];
}

// ---- GEMV with 32 RHS: out[32][NJ] += E[32][K] @ W[K][NJ] (atomic partials) ------
__global__ __launch_bounds__(256) void k_gemv32(const float* __restrict__ Wm, const float* __restrict__ Em,
                        float* out, int K, int NJ, int icpb){
  const int tid = threadIdx.x, lane = tid & 63, wv = tid >> 6;
  const int col = blockIdx.x*512 + wv*128 + lane*2;
  const long i0 = (long)blockIdx.y * icpb;
  __shared__ __align__(16) float es[128][36];
  float acc0[32], acc1[32];
  #pragma unroll
  for (int b2=0;b2<32;b2++){ acc0[b2]=0.f; acc1[b2]=0.f; }
  for (int cs=0; cs<icpb; cs+=128){
    __syncthreads();
    #pragma unroll
    for (int rep=0; rep<16; rep++){
      int x = rep*256 + tid;
      int bb = x >> 7, ii = x & 127;
      es[ii][bb] = Em[(long)bb*K + i0 + cs + ii];
    }
    __syncthreads();
    const float* wp = Wm + (i0+cs)*(long)NJ + col;
    #pragma unroll 2
    for (int ii=0; ii<128; ii++){
      float2 w2 = *(const float2*)(wp + (long)ii*NJ);
      #pragma unroll
      for (int b4=0;b4<8;b4++){
        float4 ev = *(const float4*)&es[ii][b4*4];
        acc0[b4*4+0] += w2.x*ev.x; acc1[b4*4+0] += w2.y*ev.x;
        acc0[b4*4+1] += w2.x*ev.y; acc1[b4*4+1] += w2.y*ev.y;
        acc0[b4*4+2] += w2.x*ev.z; acc1[b4*4+2] += w2.y*ev.z;
        acc0[b4*4+3] += w2.x*ev.w; acc1[b4*4+3] += w2.y*ev.w;
      }
    }
  }
  #pragma unroll
  for (int b2=0;b2<32;b2++){
    atomicAdd(&out[b2*NJ + col],     acc0[b2]);
    atomicAdd(&out[b2*NJ + col + 1], acc1[b2]);
  }
}

// ---- final output permute: out[b][o][n] = fin[b][n*16+o] -------------------------
__global__ void k_out_final(const float* __restrict__ fin, float* __restrict__ outp){
  int idx = blockIdx.x*256 + threadIdx.x;            // 131072
  int b = idx >> 12, r = idx & 4095;
  int o = r >> 8, n = r & 255;
  outp[idx] = fin[(b<<12) + (n<<4) + o];
}

extern "C" void kernel_launch(void* const* d_in, const int* in_sizes, int n_in,
                              void* d_out, int out_size, void* d_ws, size_t ws_size,
                              hipStream_t stream) {
  const float* data   = (const float*)d_in[0];
  const unsigned char* masks = (const unsigned char*)d_in[1];
  const int* ei       = (const int*)d_in[2];
  const float* gcn_w  = (const float*)d_in[3];
  const float* gcn_b  = (const float*)d_in[4];
  const float* sa_qw  = (const float*)d_in[5];
  const float* sa_qb  = (const float*)d_in[6];
  const float* sa_kw  = (const float*)d_in[7];
  const float* sa_kb  = (const float*)d_in[8];
  const float* wih    = (const float*)d_in[9];
  const float* whh    = (const float*)d_in[10];
  const float* bih    = (const float*)d_in[11];
  const float* bhh    = (const float*)d_in[12];
  const float* ta_qw  = (const float*)d_in[13];
  const float* ta_qb  = (const float*)d_in[14];
  const float* ta_kw  = (const float*)d_in[15];
  const float* ta_kb  = (const float*)d_in[16];
  const float* fc1_w  = (const float*)d_in[17];
  const float* fc1_b  = (const float*)d_in[18];
  const float* fc2_w  = (const float*)d_in[19];
  const float* fc2_b  = (const float*)d_in[20];

  float* Wp   = (float*)d_ws;
  float* dm   = Wp;                 // 131072
  float* deg  = dm + 131072;        // 256   (deg+wadj contiguous for one memset)
  float* wadj = deg + 256;          // 65536
  float* dinv = wadj + 65536;       // 256
  int*   flags= (int*)(dinv + 256); // 8 ints
  float* xw   = dinv + 256 + 8;     // 524288
  float* hb   = xw + 524288;        // 524288
  float* qb   = hb + 524288;        // 524288
  float* kb   = qb + 524288;        // 524288
  float* gi   = kb + 524288;        // 1572864
  float* rnn  = gi + 1572864;       // 524288
  float* qt   = rnn + 524288;       // 524288
  float* kt   = qt + 524288;        // 524288
  float* em   = kt + 524288;        // 1048576
  float* inter= em + 1048576;       // 131072
  float* fin  = inter + 131072;     // 131072

  float* out_final = (float*)d_out;
  float* out_sa = out_final + 131072;
  float* out_ra = out_final + 655360;

  hipMemsetAsync(deg, 0, (256 + 65536)*sizeof(float), stream);
  hipMemsetAsync(flags, 0, 8*sizeof(int), stream);

  k_detect<<<128,256,0,stream>>>(masks, ei, flags);
  k_mask<<<512,256,0,stream>>>(data, masks, flags, dm);
  k_deg<<<16,256,0,stream>>>(ei, flags, deg);
  k_dinv<<<1,256,0,stream>>>(deg, dinv, wadj);
  k_adj<<<16,256,0,stream>>>(ei, flags, dinv, wadj);
  k_xw<<<2048,256,0,stream>>>(dm, gcn_w, xw);
  k_agg<<<2048,256,0,stream>>>(wadj, xw, gcn_b, hb);
  k_qk<<<2048,256,0,stream>>>(hb, sa_qw, sa_qb, sa_kw, sa_kb, qb, kb);
  k_attn8<<<1024,256,0,stream>>>(qb, kb, hb, out_sa, 0.0625f);
  k_gi<<<8192,192,0,stream>>>(dm, wih, bih, gi);
  k_gru<<<32,192,0,stream>>>(gi, whh, bhh, rnn);
  k_qk<<<2048,256,0,stream>>>(rnn, ta_qw, ta_qb, ta_kw, ta_kb, qt, kt);
  k_attn8<<<1024,256,0,stream>>>(qt, kt, rnn, out_ra, 0.0625f);
  k_embed<<<4096,256,0,stream>>>(rnn, hb, em);
  k_binit<<<512,256,0,stream>>>(fc1_b, inter);
  { dim3 g(8,64); k_gemv32<<<g,256,0,stream>>>(fc1_w, em, inter, 32768, 4096, 512); }
  k_binit<<<512,256,0,stream>>>(fc2_b, fin);
  { dim3 g(8,32); k_gemv32<<<g,256,0,stream>>>(fc2_w, inter, fin, 4096, 4096, 128); }
  k_out_final<<<512,256,0,stream>>>(fin, out_final);
}